// Round 17
// baseline (129.931 us; speedup 1.0000x reference)
//
#include <hip/hip_runtime.h>
#include <hip/hip_bf16.h>

typedef __bf16 bf16x8 __attribute__((ext_vector_type(8)));
typedef float f32x4 __attribute__((ext_vector_type(4)));
typedef float f32x16 __attribute__((ext_vector_type(16)));
typedef unsigned u32x4 __attribute__((ext_vector_type(4)));
#define MFMA16 __builtin_amdgcn_mfma_f32_16x16x32_bf16
#define MFMA32 __builtin_amdgcn_mfma_f32_32x32x16_bf16

static constexpr int Bsz = 4, T = 4096, C = 1024, H = 128;
static constexpr int BT = Bsz * T; // 16384

__device__ __forceinline__ void gl2lds16(const __bf16* g, __bf16* l) {
    __builtin_amdgcn_global_load_lds(
        (const __attribute__((address_space(1))) void*)g,
        (__attribute__((address_space(3))) void*)l, 16, 0, 0);
}

__device__ __forceinline__ unsigned pk2(float a, float b) {
    unsigned short ua = __builtin_bit_cast(unsigned short, (__bf16)a);
    unsigned short ub = __builtin_bit_cast(unsigned short, (__bf16)b);
    return (unsigned)ua | ((unsigned)ub << 16);
}

// -------- kernel 0: W fp32[1024][128]x3 -> WTall bf16[384][1024] -----------
__global__ __launch_bounds__(256) void k_wprep(
    const float* __restrict__ Wq, const float* __restrict__ Wk,
    const float* __restrict__ Wv, __bf16* __restrict__ WTall)
{
    int idx = blockIdx.x * 256 + threadIdx.x;   // 0..393215
    int n = idx >> 10, k = idx & 1023;
    int mat = n >> 7, col = n & 127;
    const float* W = mat == 0 ? Wq : (mat == 1 ? Wk : Wv);
    float s = (mat == 1) ? 0.045084220f : 1.0f;  // 1/32 * log2(e)
    WTall[idx] = (__bf16)(W[k * H + col] * s);
}

// -------- kernel 1: QKV projection GEMM, N-split, CU-paired ny -------------
__global__ __launch_bounds__(512) void k_proj(
    const float* __restrict__ X, const __bf16* __restrict__ WTall,
    __bf16* __restrict__ Qp, __bf16* __restrict__ Kp, __bf16* __restrict__ VT)
{
    union Smem {
        struct { __bf16 a[2][64 * 64]; __bf16 b[2][192 * 64]; } s; // 64KB
        __bf16 vt_e[128][72];
    };
    __shared__ Smem su;

    const int tid = threadIdx.x;
    const int lane = tid & 63, w = tid >> 6;
    const int c = lane & 15, hi = lane >> 4;
    const int wm = w >> 2, wn = w & 3;
    const int ny = blockIdx.x >> 8;              // 0 or 1
    const int m0 = (blockIdx.x & 255) * 64;
    const int xorv = (c & 7) << 3;

    const int arow = tid >> 3, ac8 = tid & 7;
    const float* aSrc = X + (size_t)(m0 + arow) * C + ac8 * 8;
    const int aDst = arow * 64 + ((ac8 * 8) ^ ((arow & 7) << 3));
    const int brl = lane >> 3, bch = lane & 7;
    const __bf16* Wbase = WTall + (size_t)ny * 192 * 1024;

    f32x4 acc[2][3];
    #pragma unroll
    for (int i = 0; i < 2; ++i)
        #pragma unroll
        for (int j = 0; j < 3; ++j) acc[i][j] = (f32x4){0.f, 0.f, 0.f, 0.f};

    #pragma unroll
    for (int ib = 0; ib < 3; ++ib) {
        int row = w * 24 + ib * 8 + brl;
        int ch = bch ^ (row & 7);
        gl2lds16(Wbase + (size_t)row * 1024 + ch * 8, &su.s.b[0][(w * 3 + ib) * 512]);
    }
    {
        float4 f0 = *(const float4*)aSrc;
        float4 f1 = *(const float4*)(aSrc + 4);
        bf16x8 av;
        av[0] = (__bf16)f0.x; av[1] = (__bf16)f0.y; av[2] = (__bf16)f0.z; av[3] = (__bf16)f0.w;
        av[4] = (__bf16)f1.x; av[5] = (__bf16)f1.y; av[6] = (__bf16)f1.z; av[7] = (__bf16)f1.w;
        *(bf16x8*)&su.s.a[0][aDst] = av;
    }
    __syncthreads();

    for (int t = 0; t < 16; ++t) {
        int cur = t & 1;
        float4 g0, g1;
        if (t < 15) {
            int k0 = (t + 1) * 64;
            #pragma unroll
            for (int ib = 0; ib < 3; ++ib) {
                int row = w * 24 + ib * 8 + brl;
                int ch = bch ^ (row & 7);
                gl2lds16(Wbase + (size_t)row * 1024 + k0 + ch * 8,
                         &su.s.b[cur ^ 1][(w * 3 + ib) * 512]);
            }
            g0 = *(const float4*)(aSrc + k0);
            g1 = *(const float4*)(aSrc + k0 + 4);
        }
        #pragma unroll
        for (int kk = 0; kk < 2; ++kk) {
            bf16x8 a0 = *(const bf16x8*)&su.s.a[cur][(wm * 32 + c) * 64 + ((kk * 32 + hi * 8) ^ xorv)];
            bf16x8 a1 = *(const bf16x8*)&su.s.a[cur][(wm * 32 + 16 + c) * 64 + ((kk * 32 + hi * 8) ^ xorv)];
            #pragma unroll
            for (int fn = 0; fn < 3; ++fn) {
                bf16x8 bb = *(const bf16x8*)&su.s.b[cur][(wn * 48 + fn * 16 + c) * 64 + ((kk * 32 + hi * 8) ^ xorv)];
                acc[0][fn] = MFMA16(a0, bb, acc[0][fn], 0, 0, 0);
                acc[1][fn] = MFMA16(a1, bb, acc[1][fn], 0, 0, 0);
            }
        }
        if (t < 15) {
            bf16x8 av;
            av[0] = (__bf16)g0.x; av[1] = (__bf16)g0.y; av[2] = (__bf16)g0.z; av[3] = (__bf16)g0.w;
            av[4] = (__bf16)g1.x; av[5] = (__bf16)g1.y; av[6] = (__bf16)g1.z; av[7] = (__bf16)g1.w;
            *(bf16x8*)&su.s.a[cur ^ 1][aDst] = av;
        }
        __syncthreads();
    }

    #pragma unroll
    for (int mi = 0; mi < 2; ++mi) {
        int rowl = wm * 32 + mi * 16 + hi * 4;
        #pragma unroll
        for (int fn = 0; fn < 3; ++fn) {
            int nb = ny * 192 + wn * 48 + fn * 16;
            int mat = nb >> 7, colb = (nb & 127) + c;
            #pragma unroll
            for (int r = 0; r < 4; ++r) {
                __bf16 v = (__bf16)acc[mi][fn][r];
                if (mat == 0)      Qp[(size_t)(m0 + rowl + r) * H + colb] = v;
                else if (mat == 1) Kp[(size_t)(m0 + rowl + r) * H + colb] = v;
                else               su.vt_e[colb][rowl + r] = v;
            }
        }
    }
    __syncthreads();
    if (ny == 1) {
        int d = tid >> 2, tc = (tid & 3) * 16;
        int b = m0 >> 12, tl = m0 & (T - 1);
        __bf16* dst = VT + ((size_t)b * H + d) * T + tl + tc;
        const __bf16* s2 = &su.vt_e[d][tc];
        *(uint4*)dst = *(const uint4*)s2;
        *(uint4*)(dst + 8) = *(const uint4*)(s2 + 8);
    }
}

// -------- kernel 2: causal attention, swapped-QK, UNPAIRED for 2 blocks/CU -
// 512 blocks x 256 thr (4 waves = wm(t-half) x ws(s-half)). Block = one
// 64-row q-tile (b, part p, jj), longest-first: jj = 63 - (bi>>3).
// Wave steps i = p, p+2, ... 2 blocks/CU co-resident (VGPR ~116+acc,
// LDS 34KB) -> 2 waves/SIMD hide the per-step latency chain.
// QK computed swapped -> lane holds P[s][t=lane&31]; P->PV A-frag via
// pk2 + shfl_xor(32) (no LDS). Direct-L2 Q/V; XCD pin bi&7=(b<<1)|p.
__global__ __launch_bounds__(256) void k_attn(
    const __bf16* __restrict__ Ka, const __bf16* __restrict__ Qb,
    const __bf16* __restrict__ VT, float* __restrict__ Out,
    float* __restrict__ Po, float* __restrict__ Pl)
{
    __shared__ float oacc[64][132];
    __shared__ float sml[4][32];

    const int tid = threadIdx.x, lane = tid & 63, w = tid >> 6;
    const int t31 = lane & 31, hi5 = lane >> 5;
    const int wm = w >> 1, ws = w & 1;

    const int bi = blockIdx.x;
    const int p = bi & 1, b = (bi >> 1) & 3, jj = 63 - (bi >> 3);

    const __bf16* Kb  = Ka + (size_t)b * T * H;
    const __bf16* Qbb = Qb + (size_t)b * T * H;
    const __bf16* Vb  = VT + (size_t)b * H * T;

    const int t0 = jj * 64;
    const int nsteps = jj + 1;          // 64-wide s-steps
    const int rbase = t0 + wm * 32;     // wave's first K-row
    const int tg = rbase + t31;         // this lane's t (output row)

    // K B-fragments: wave's 32 K-rows, full H (32 VGPRs)
    bf16x8 kb[8];
    #pragma unroll
    for (int kc = 0; kc < 8; ++kc)
        kb[kc] = *(const bf16x8*)(Kb + (size_t)(rbase + t31) * H + kc * 16 + hi5 * 8);

    f32x16 oc[4];
    #pragma unroll
    for (int dn = 0; dn < 4; ++dn)
        #pragma unroll
        for (int r = 0; r < 16; ++r) oc[dn][r] = 0.f;
    float ol = 0.f;

    for (int i = p; i < nsteps; i += 2) {
        const int sbase = i * 64 + ws * 32;
        // Q A-frags (32 s-rows) + V B-frags, direct from L2
        bf16x8 qa[8];
        #pragma unroll
        for (int kc = 0; kc < 8; ++kc)
            qa[kc] = *(const bf16x8*)(Qbb + (size_t)(sbase + t31) * H + kc * 16 + hi5 * 8);
        bf16x8 vb[4][2];
        #pragma unroll
        for (int dn = 0; dn < 4; ++dn)
            #pragma unroll
            for (int ks = 0; ks < 2; ++ks)
                vb[dn][ks] = *(const bf16x8*)(Vb + (size_t)(dn * 32 + t31) * T + sbase + ks * 16 + hi5 * 8);

        // QK^T (swapped): C[s][t], two 4-deep chains
        f32x16 accA, accB;
        #pragma unroll
        for (int r = 0; r < 16; ++r) { accA[r] = 0.f; accB[r] = 0.f; }
        #pragma unroll
        for (int kc = 0; kc < 4; ++kc) accA = MFMA32(qa[kc], kb[kc], accA, 0, 0, 0);
        #pragma unroll
        for (int kc = 4; kc < 8; ++kc) accB = MFMA32(qa[kc], kb[kc], accB, 0, 0, 0);

        // exp2 + causal mask + in-lane row sums
        const bool dz = (sbase + 31 >= rbase);
        float pv[16];
        #pragma unroll
        for (int r = 0; r < 16; ++r) {
            float e = __builtin_amdgcn_exp2f(accA[r] + accB[r]);
            if (dz) {
                int sg = sbase + (r & 3) + 8 * (r >> 2) + 4 * hi5;
                if (sg > tg) e = 0.f;
            }
            pv[r] = e;
        }
        float rs = ((pv[0] + pv[1]) + (pv[2] + pv[3])) + ((pv[4] + pv[5]) + (pv[6] + pv[7]))
                 + ((pv[8] + pv[9]) + (pv[10] + pv[11])) + ((pv[12] + pv[13]) + (pv[14] + pv[15]));
        ol += rs;

        // pack P -> bf16 A-frags via lane^32 exchange (no LDS)
        unsigned x1 = pk2(pv[0], pv[1]),  x2 = pk2(pv[2], pv[3]);
        unsigned y1 = pk2(pv[4], pv[5]),  y2 = pk2(pv[6], pv[7]);
        unsigned x3 = pk2(pv[8], pv[9]),  x4 = pk2(pv[10], pv[11]);
        unsigned y3 = pk2(pv[12], pv[13]), y4 = pk2(pv[14], pv[15]);
        unsigned sx1 = __shfl_xor((int)x1, 32), sx2 = __shfl_xor((int)x2, 32);
        unsigned sy1 = __shfl_xor((int)y1, 32), sy2 = __shfl_xor((int)y2, 32);
        unsigned sx3 = __shfl_xor((int)x3, 32), sx4 = __shfl_xor((int)x4, 32);
        unsigned sy3 = __shfl_xor((int)y3, 32), sy4 = __shfl_xor((int)y4, 32);
        u32x4 wA, wB;
        wA[0] = hi5 ? sy1 : x1;  wA[1] = hi5 ? sy2 : x2;
        wA[2] = hi5 ? y1 : sx1;  wA[3] = hi5 ? y2 : sx2;
        wB[0] = hi5 ? sy3 : x3;  wB[1] = hi5 ? sy4 : x4;
        wB[2] = hi5 ? y3 : sx3;  wB[3] = hi5 ? y4 : sx4;
        bf16x8 paA = __builtin_bit_cast(bf16x8, wA);
        bf16x8 paB = __builtin_bit_cast(bf16x8, wB);

        // PV: O[t][d] += P(32x32) @ V(32x128)
        #pragma unroll
        for (int dn = 0; dn < 4; ++dn) {
            oc[dn] = MFMA32(paA, vb[dn][0], oc[dn], 0, 0, 0);
            oc[dn] = MFMA32(paB, vb[dn][1], oc[dn], 0, 0, 0);
        }
    }

    // ---- merge the two hi-halves' row sums, then ws pairs via LDS ----
    ol += __shfl_xor(ol, 32);
    if (lane < 32) sml[w][lane] = ol;

    if (ws == 0) {
        #pragma unroll
        for (int dn = 0; dn < 4; ++dn)
            #pragma unroll
            for (int r = 0; r < 16; ++r) {
                int row = wm * 32 + (r & 3) + 8 * (r >> 2) + 4 * hi5;
                oacc[row][dn * 32 + t31] = oc[dn][r];
            }
    }
    __syncthreads();
    if (ws == 1) {
        #pragma unroll
        for (int dn = 0; dn < 4; ++dn)
            #pragma unroll
            for (int r = 0; r < 16; ++r) {
                int row = wm * 32 + (r & 3) + 8 * (r >> 2) + 4 * hi5;
                oacc[row][dn * 32 + t31] += oc[dn][r];
            }
    }
    __syncthreads();
    {
        int row = tid >> 2, cq = (tid & 3) * 4;     // row 0..63
        float L = sml[(row >> 5) * 2][row & 31] + sml[(row >> 5) * 2 + 1][row & 31];
        float* dst = (p == 0 ? Out : Po) + ((size_t)b * T + t0 + row) * H;
        #pragma unroll
        for (int k = 0; k < 8; ++k) {
            int col = cq + k * 16;
            float4 v;
            v.x = oacc[row][col];
            v.y = oacc[row][col + 1];
            v.z = oacc[row][col + 2];
            v.w = oacc[row][col + 3];
            *(float4*)(dst + col) = v;
        }
        if ((tid & 3) == 0) Pl[(size_t)p * BT + b * T + t0 + row] = L;
    }
}

// -------- kernel 3: merge parts + normalize --------------------------------
__global__ __launch_bounds__(256) void k_merge(
    float* __restrict__ Out, const float* __restrict__ Po,
    const float* __restrict__ Pl)
{
    size_t idx = ((size_t)blockIdx.x * 256 + threadIdx.x) * 8;
    size_t row = idx >> 7;
    float inv = 1.0f / (Pl[row] + Pl[BT + row]);
    float4 a0 = *(const float4*)(Out + idx);
    float4 a1 = *(const float4*)(Out + idx + 4);
    float4 p0 = *(const float4*)(Po + idx);
    float4 p1 = *(const float4*)(Po + idx + 4);
    float4 r0, r1;
    r0.x = (a0.x + p0.x) * inv; r0.y = (a0.y + p0.y) * inv;
    r0.z = (a0.z + p0.z) * inv; r0.w = (a0.w + p0.w) * inv;
    r1.x = (a1.x + p1.x) * inv; r1.y = (a1.y + p1.y) * inv;
    r1.z = (a1.z + p1.z) * inv; r1.w = (a1.w + p1.w) * inv;
    *(float4*)(Out + idx)     = r0;
    *(float4*)(Out + idx + 4) = r1;
}

extern "C" void kernel_launch(void* const* d_in, const int* in_sizes, int n_in,
                              void* d_out, int out_size, void* d_ws, size_t ws_size,
                              hipStream_t stream) {
    const float* ix = (const float*)d_in[0];
    const float* Wq = (const float*)d_in[1];
    const float* Wk = (const float*)d_in[2];
    const float* Wv = (const float*)d_in[3];
    float* out = (float*)d_out;

    __bf16* WTall = (__bf16*)d_ws;                    // 384*1024
    __bf16* Qp = WTall + 393216;                      // [BT][H]
    __bf16* Kp = Qp + (size_t)BT * H;
    __bf16* VT = Kp + (size_t)BT * H;                 // [B][H][T]
    float*  Po = (float*)(VT + (size_t)BT * H);       // [BT][H] fp32
    float*  Pl = Po + (size_t)BT * H;                 // [2][BT]
    // total ws ~21.9 MB (known-good layout)

    k_wprep<<<dim3(1536), 256, 0, stream>>>(Wq, Wk, Wv, WTall);
    k_proj<<<dim3(512), 512, 0, stream>>>(ix, WTall, Qp, Kp, VT);
    k_attn<<<dim3(512), 256, 0, stream>>>(Kp, Qp, VT, out, Po, Pl);
    k_merge<<<dim3(1024), 256, 0, stream>>>(out, Po, Pl);
}

// Round 18
// 105.992 us; speedup vs baseline: 1.2259x; 1.2259x over previous
//
#include <hip/hip_runtime.h>
#include <hip/hip_bf16.h>

typedef __bf16 bf16x8 __attribute__((ext_vector_type(8)));
typedef float f32x4 __attribute__((ext_vector_type(4)));
typedef float f32x16 __attribute__((ext_vector_type(16)));
typedef unsigned u32x4 __attribute__((ext_vector_type(4)));
#define MFMA16 __builtin_amdgcn_mfma_f32_16x16x32_bf16
#define MFMA32 __builtin_amdgcn_mfma_f32_32x32x16_bf16

static constexpr int Bsz = 4, T = 4096, C = 1024, H = 128;
static constexpr int BT = Bsz * T; // 16384

__device__ __forceinline__ void gl2lds16(const __bf16* g, __bf16* l) {
    __builtin_amdgcn_global_load_lds(
        (const __attribute__((address_space(1))) void*)g,
        (__attribute__((address_space(3))) void*)l, 16, 0, 0);
}

__device__ __forceinline__ unsigned pk2(float a, float b) {
    unsigned short ua = __builtin_bit_cast(unsigned short, (__bf16)a);
    unsigned short ub = __builtin_bit_cast(unsigned short, (__bf16)b);
    return (unsigned)ua | ((unsigned)ub << 16);
}

// -------- kernel 0: W fp32[1024][128]x3 -> WTall bf16[384][1024] -----------
__global__ __launch_bounds__(256) void k_wprep(
    const float* __restrict__ Wq, const float* __restrict__ Wk,
    const float* __restrict__ Wv, __bf16* __restrict__ WTall)
{
    int idx = blockIdx.x * 256 + threadIdx.x;   // 0..393215
    int n = idx >> 10, k = idx & 1023;
    int mat = n >> 7, col = n & 127;
    const float* W = mat == 0 ? Wq : (mat == 1 ? Wk : Wv);
    float s = (mat == 1) ? 0.045084220f : 1.0f;  // 1/32 * log2(e)
    WTall[idx] = (__bf16)(W[k * H + col] * s);
}

// -------- kernel 1: QKV projection GEMM, N-split, CU-paired ny -------------
__global__ __launch_bounds__(512) void k_proj(
    const float* __restrict__ X, const __bf16* __restrict__ WTall,
    __bf16* __restrict__ Qp, __bf16* __restrict__ Kp, __bf16* __restrict__ VT)
{
    union Smem {
        struct { __bf16 a[2][64 * 64]; __bf16 b[2][192 * 64]; } s; // 64KB
        __bf16 vt_e[128][72];
    };
    __shared__ Smem su;

    const int tid = threadIdx.x;
    const int lane = tid & 63, w = tid >> 6;
    const int c = lane & 15, hi = lane >> 4;
    const int wm = w >> 2, wn = w & 3;
    const int ny = blockIdx.x >> 8;              // 0 or 1
    const int m0 = (blockIdx.x & 255) * 64;
    const int xorv = (c & 7) << 3;

    const int arow = tid >> 3, ac8 = tid & 7;
    const float* aSrc = X + (size_t)(m0 + arow) * C + ac8 * 8;
    const int aDst = arow * 64 + ((ac8 * 8) ^ ((arow & 7) << 3));
    const int brl = lane >> 3, bch = lane & 7;
    const __bf16* Wbase = WTall + (size_t)ny * 192 * 1024;

    f32x4 acc[2][3];
    #pragma unroll
    for (int i = 0; i < 2; ++i)
        #pragma unroll
        for (int j = 0; j < 3; ++j) acc[i][j] = (f32x4){0.f, 0.f, 0.f, 0.f};

    #pragma unroll
    for (int ib = 0; ib < 3; ++ib) {
        int row = w * 24 + ib * 8 + brl;
        int ch = bch ^ (row & 7);
        gl2lds16(Wbase + (size_t)row * 1024 + ch * 8, &su.s.b[0][(w * 3 + ib) * 512]);
    }
    {
        float4 f0 = *(const float4*)aSrc;
        float4 f1 = *(const float4*)(aSrc + 4);
        bf16x8 av;
        av[0] = (__bf16)f0.x; av[1] = (__bf16)f0.y; av[2] = (__bf16)f0.z; av[3] = (__bf16)f0.w;
        av[4] = (__bf16)f1.x; av[5] = (__bf16)f1.y; av[6] = (__bf16)f1.z; av[7] = (__bf16)f1.w;
        *(bf16x8*)&su.s.a[0][aDst] = av;
    }
    __syncthreads();

    for (int t = 0; t < 16; ++t) {
        int cur = t & 1;
        float4 g0, g1;
        if (t < 15) {
            int k0 = (t + 1) * 64;
            #pragma unroll
            for (int ib = 0; ib < 3; ++ib) {
                int row = w * 24 + ib * 8 + brl;
                int ch = bch ^ (row & 7);
                gl2lds16(Wbase + (size_t)row * 1024 + k0 + ch * 8,
                         &su.s.b[cur ^ 1][(w * 3 + ib) * 512]);
            }
            g0 = *(const float4*)(aSrc + k0);
            g1 = *(const float4*)(aSrc + k0 + 4);
        }
        #pragma unroll
        for (int kk = 0; kk < 2; ++kk) {
            bf16x8 a0 = *(const bf16x8*)&su.s.a[cur][(wm * 32 + c) * 64 + ((kk * 32 + hi * 8) ^ xorv)];
            bf16x8 a1 = *(const bf16x8*)&su.s.a[cur][(wm * 32 + 16 + c) * 64 + ((kk * 32 + hi * 8) ^ xorv)];
            #pragma unroll
            for (int fn = 0; fn < 3; ++fn) {
                bf16x8 bb = *(const bf16x8*)&su.s.b[cur][(wn * 48 + fn * 16 + c) * 64 + ((kk * 32 + hi * 8) ^ xorv)];
                acc[0][fn] = MFMA16(a0, bb, acc[0][fn], 0, 0, 0);
                acc[1][fn] = MFMA16(a1, bb, acc[1][fn], 0, 0, 0);
            }
        }
        if (t < 15) {
            bf16x8 av;
            av[0] = (__bf16)g0.x; av[1] = (__bf16)g0.y; av[2] = (__bf16)g0.z; av[3] = (__bf16)g0.w;
            av[4] = (__bf16)g1.x; av[5] = (__bf16)g1.y; av[6] = (__bf16)g1.z; av[7] = (__bf16)g1.w;
            *(bf16x8*)&su.s.a[cur ^ 1][aDst] = av;
        }
        __syncthreads();
    }

    #pragma unroll
    for (int mi = 0; mi < 2; ++mi) {
        int rowl = wm * 32 + mi * 16 + hi * 4;
        #pragma unroll
        for (int fn = 0; fn < 3; ++fn) {
            int nb = ny * 192 + wn * 48 + fn * 16;
            int mat = nb >> 7, colb = (nb & 127) + c;
            #pragma unroll
            for (int r = 0; r < 4; ++r) {
                __bf16 v = (__bf16)acc[mi][fn][r];
                if (mat == 0)      Qp[(size_t)(m0 + rowl + r) * H + colb] = v;
                else if (mat == 1) Kp[(size_t)(m0 + rowl + r) * H + colb] = v;
                else               su.vt_e[colb][rowl + r] = v;
            }
        }
    }
    __syncthreads();
    if (ny == 1) {
        int d = tid >> 2, tc = (tid & 3) * 16;
        int b = m0 >> 12, tl = m0 & (T - 1);
        __bf16* dst = VT + ((size_t)b * H + d) * T + tl + tc;
        const __bf16* s2 = &su.vt_e[d][tc];
        *(uint4*)dst = *(const uint4*)s2;
        *(uint4*)(dst + 8) = *(const uint4*)(s2 + 8);
    }
}

// -------- kernel 2: causal attention, 32-row tiles paired, 8 waves ---------
// 256 blocks x 512 thr. Block = (b, pair v): does 32-row q-tiles v and 127-v
// (65 steps total -> perfect balance, every block equal). 8 waves =
// ws(2 s-col halves) x sp(4 step parities); wave takes steps i = sp, sp+4...
// of its ws half. 1 block/CU, 2 waves/SIMD. Swapped-QK inner loop (lane-
// local t, in-register P via pk2+shfl_xor(32), no LDS in loop). Everything
// merges in-block -> final normalized Out written directly (no Po/Pl/merge).
__global__ __launch_bounds__(512) void k_attn(
    const __bf16* __restrict__ Ka, const __bf16* __restrict__ Qb,
    const __bf16* __restrict__ VT, float* __restrict__ Out)
{
    __shared__ float oaccA[32][132];   // ws=0 accumulation
    __shared__ float oaccB[32][132];   // ws=1 accumulation
    __shared__ float sml[8][32];

    const int tid = threadIdx.x, lane = tid & 63, w = tid >> 6;  // w 0..7
    const int t31 = lane & 31, hi5 = lane >> 5;
    const int ws = w >> 2, sp = w & 3;

    const int bi = blockIdx.x;
    const int b = bi & 3, vpr = bi >> 2;   // vpr in 0..63

    const __bf16* Kb  = Ka + (size_t)b * T * H;
    const __bf16* Qbb = Qb + (size_t)b * T * H;
    const __bf16* Vb  = VT + (size_t)b * H * T;

    #pragma unroll 1
    for (int half = 0; half < 2; ++half) {
        const int v  = half ? (127 - vpr) : vpr;   // 32-row tile index
        const int t0 = v * 32;
        const int nsteps = (v >> 1) + 1;           // 64-wide s-steps
        const int tg = t0 + t31;                   // this lane's t row

        // K B-fragments: tile's 32 K-rows, full H (32 VGPRs)
        bf16x8 kb[8];
        #pragma unroll
        for (int kc = 0; kc < 8; ++kc)
            kb[kc] = *(const bf16x8*)(Kb + (size_t)(t0 + t31) * H + kc * 16 + hi5 * 8);

        f32x16 oc[4];
        #pragma unroll
        for (int dn = 0; dn < 4; ++dn)
            #pragma unroll
            for (int r = 0; r < 16; ++r) oc[dn][r] = 0.f;
        float ol = 0.f;

        for (int i = sp; i < nsteps; i += 4) {
            const int sbase = i * 64 + ws * 32;
            // Q A-frags (32 s-rows) + V B-frags, direct from L2
            bf16x8 qa[8];
            #pragma unroll
            for (int kc = 0; kc < 8; ++kc)
                qa[kc] = *(const bf16x8*)(Qbb + (size_t)(sbase + t31) * H + kc * 16 + hi5 * 8);
            bf16x8 vb[4][2];
            #pragma unroll
            for (int dn = 0; dn < 4; ++dn)
                #pragma unroll
                for (int ks = 0; ks < 2; ++ks)
                    vb[dn][ks] = *(const bf16x8*)(Vb + (size_t)(dn * 32 + t31) * T + sbase + ks * 16 + hi5 * 8);

            // QK^T (swapped): C[s][t], two 4-deep chains
            f32x16 accA, accB;
            #pragma unroll
            for (int r = 0; r < 16; ++r) { accA[r] = 0.f; accB[r] = 0.f; }
            #pragma unroll
            for (int kc = 0; kc < 4; ++kc) accA = MFMA32(qa[kc], kb[kc], accA, 0, 0, 0);
            #pragma unroll
            for (int kc = 4; kc < 8; ++kc) accB = MFMA32(qa[kc], kb[kc], accB, 0, 0, 0);

            // exp2 + causal mask + in-lane row sums
            const bool dz = (sbase + 31 >= t0);
            float pv[16];
            #pragma unroll
            for (int r = 0; r < 16; ++r) {
                float e = __builtin_amdgcn_exp2f(accA[r] + accB[r]);
                if (dz) {
                    int sg = sbase + (r & 3) + 8 * (r >> 2) + 4 * hi5;
                    if (sg > tg) e = 0.f;
                }
                pv[r] = e;
            }
            float rs = ((pv[0] + pv[1]) + (pv[2] + pv[3])) + ((pv[4] + pv[5]) + (pv[6] + pv[7]))
                     + ((pv[8] + pv[9]) + (pv[10] + pv[11])) + ((pv[12] + pv[13]) + (pv[14] + pv[15]));
            ol += rs;

            // pack P -> bf16 A-frags via lane^32 exchange (no LDS)
            unsigned x1 = pk2(pv[0], pv[1]),  x2 = pk2(pv[2], pv[3]);
            unsigned y1 = pk2(pv[4], pv[5]),  y2 = pk2(pv[6], pv[7]);
            unsigned x3 = pk2(pv[8], pv[9]),  x4 = pk2(pv[10], pv[11]);
            unsigned y3 = pk2(pv[12], pv[13]), y4 = pk2(pv[14], pv[15]);
            unsigned sx1 = __shfl_xor((int)x1, 32), sx2 = __shfl_xor((int)x2, 32);
            unsigned sy1 = __shfl_xor((int)y1, 32), sy2 = __shfl_xor((int)y2, 32);
            unsigned sx3 = __shfl_xor((int)x3, 32), sx4 = __shfl_xor((int)x4, 32);
            unsigned sy3 = __shfl_xor((int)y3, 32), sy4 = __shfl_xor((int)y4, 32);
            u32x4 wA, wB;
            wA[0] = hi5 ? sy1 : x1;  wA[1] = hi5 ? sy2 : x2;
            wA[2] = hi5 ? y1 : sx1;  wA[3] = hi5 ? y2 : sx2;
            wB[0] = hi5 ? sy3 : x3;  wB[1] = hi5 ? sy4 : x4;
            wB[2] = hi5 ? y3 : sx3;  wB[3] = hi5 ? y4 : sx4;
            bf16x8 paA = __builtin_bit_cast(bf16x8, wA);
            bf16x8 paB = __builtin_bit_cast(bf16x8, wB);

            // PV: O[t][d] += P(32x32) @ V(32x128)
            #pragma unroll
            for (int dn = 0; dn < 4; ++dn) {
                oc[dn] = MFMA32(paA, vb[dn][0], oc[dn], 0, 0, 0);
                oc[dn] = MFMA32(paB, vb[dn][1], oc[dn], 0, 0, 0);
            }
        }

        // ---- in-block merge of all 8 waves, normalize, write Out ----
        ol += __shfl_xor(ol, 32);
        if (lane < 32) sml[w][lane] = ol;

        // 4 sp-stages; ws=0 -> oaccA, ws=1 -> oaccB run concurrently
        for (int g = 0; g < 4; ++g) {
            __syncthreads();
            if (sp == g) {
                float* oa = (ws == 0) ? &oaccA[0][0] : &oaccB[0][0];
                #pragma unroll
                for (int dn = 0; dn < 4; ++dn)
                    #pragma unroll
                    for (int r = 0; r < 16; ++r) {
                        int row = (r & 3) + 8 * (r >> 2) + 4 * hi5;
                        int col = dn * 32 + t31;
                        if (g == 0) oa[row * 132 + col]  = oc[dn][r];
                        else        oa[row * 132 + col] += oc[dn][r];
                    }
            }
        }
        __syncthreads();
        {
            int row = tid >> 4, col0 = (tid & 15) * 8;   // 32 rows x 128 cols
            float L = sml[0][row] + sml[1][row] + sml[2][row] + sml[3][row]
                    + sml[4][row] + sml[5][row] + sml[6][row] + sml[7][row];
            float inv = 1.0f / L;
            float* dst = Out + ((size_t)b * T + t0 + row) * H + col0;
            float4 v0, v1;
            v0.x = (oaccA[row][col0]     + oaccB[row][col0])     * inv;
            v0.y = (oaccA[row][col0 + 1] + oaccB[row][col0 + 1]) * inv;
            v0.z = (oaccA[row][col0 + 2] + oaccB[row][col0 + 2]) * inv;
            v0.w = (oaccA[row][col0 + 3] + oaccB[row][col0 + 3]) * inv;
            v1.x = (oaccA[row][col0 + 4] + oaccB[row][col0 + 4]) * inv;
            v1.y = (oaccA[row][col0 + 5] + oaccB[row][col0 + 5]) * inv;
            v1.z = (oaccA[row][col0 + 6] + oaccB[row][col0 + 6]) * inv;
            v1.w = (oaccA[row][col0 + 7] + oaccB[row][col0 + 7]) * inv;
            *(float4*)dst       = v0;
            *(float4*)(dst + 4) = v1;
        }
        __syncthreads();   // oacc/sml safe to reuse in next half
    }
}

extern "C" void kernel_launch(void* const* d_in, const int* in_sizes, int n_in,
                              void* d_out, int out_size, void* d_ws, size_t ws_size,
                              hipStream_t stream) {
    const float* ix = (const float*)d_in[0];
    const float* Wq = (const float*)d_in[1];
    const float* Wk = (const float*)d_in[2];
    const float* Wv = (const float*)d_in[3];
    float* out = (float*)d_out;

    __bf16* WTall = (__bf16*)d_ws;                    // 384*1024
    __bf16* Qp = WTall + 393216;                      // [BT][H]
    __bf16* Kp = Qp + (size_t)BT * H;
    __bf16* VT = Kp + (size_t)BT * H;                 // [B][H][T]
    // total ws ~13.4 MB

    k_wprep<<<dim3(1536), 256, 0, stream>>>(Wq, Wk, Wv, WTall);
    k_proj<<<dim3(512), 512, 0, stream>>>(ix, WTall, Qp, Kp, VT);
    k_attn<<<dim3(256), 512, 0, stream>>>(Kp, Qp, VT, out);
}

// Round 19
// 89.605 us; speedup vs baseline: 1.4500x; 1.1829x over previous
//
#include <hip/hip_runtime.h>
#include <hip/hip_bf16.h>

typedef __bf16 bf16x8 __attribute__((ext_vector_type(8)));
typedef float f32x4 __attribute__((ext_vector_type(4)));
typedef float f32x16 __attribute__((ext_vector_type(16)));
typedef unsigned u32x4 __attribute__((ext_vector_type(4)));
#define MFMA16 __builtin_amdgcn_mfma_f32_16x16x32_bf16
#define MFMA32 __builtin_amdgcn_mfma_f32_32x32x16_bf16

static constexpr int Bsz = 4, T = 4096, C = 1024, H = 128;
static constexpr int BT = Bsz * T; // 16384

__device__ __forceinline__ void gl2lds16(const __bf16* g, __bf16* l) {
    __builtin_amdgcn_global_load_lds(
        (const __attribute__((address_space(1))) void*)g,
        (__attribute__((address_space(3))) void*)l, 16, 0, 0);
}

__device__ __forceinline__ unsigned pk2(float a, float b) {
    unsigned short ua = __builtin_bit_cast(unsigned short, (__bf16)a);
    unsigned short ub = __builtin_bit_cast(unsigned short, (__bf16)b);
    return (unsigned)ua | ((unsigned)ub << 16);
}

// -------- kernel 0: W fp32[1024][128]x3 -> WTall bf16[384][1024] -----------
__global__ __launch_bounds__(256) void k_wprep(
    const float* __restrict__ Wq, const float* __restrict__ Wk,
    const float* __restrict__ Wv, __bf16* __restrict__ WTall)
{
    int idx = blockIdx.x * 256 + threadIdx.x;   // 0..393215
    int n = idx >> 10, k = idx & 1023;
    int mat = n >> 7, col = n & 127;
    const float* W = mat == 0 ? Wq : (mat == 1 ? Wk : Wv);
    float s = (mat == 1) ? 0.045084220f : 1.0f;  // 1/32 * log2(e)
    WTall[idx] = (__bf16)(W[k * H + col] * s);
}

// -------- kernel 1: QKV projection GEMM, N-split, CU-paired ny -------------
__global__ __launch_bounds__(512) void k_proj(
    const float* __restrict__ X, const __bf16* __restrict__ WTall,
    __bf16* __restrict__ Qp, __bf16* __restrict__ Kp, __bf16* __restrict__ VT)
{
    union Smem {
        struct { __bf16 a[2][64 * 64]; __bf16 b[2][192 * 64]; } s; // 64KB
        __bf16 vt_e[128][72];
    };
    __shared__ Smem su;

    const int tid = threadIdx.x;
    const int lane = tid & 63, w = tid >> 6;
    const int c = lane & 15, hi = lane >> 4;
    const int wm = w >> 2, wn = w & 3;
    const int ny = blockIdx.x >> 8;              // 0 or 1
    const int m0 = (blockIdx.x & 255) * 64;
    const int xorv = (c & 7) << 3;

    const int arow = tid >> 3, ac8 = tid & 7;
    const float* aSrc = X + (size_t)(m0 + arow) * C + ac8 * 8;
    const int aDst = arow * 64 + ((ac8 * 8) ^ ((arow & 7) << 3));
    const int brl = lane >> 3, bch = lane & 7;
    const __bf16* Wbase = WTall + (size_t)ny * 192 * 1024;

    f32x4 acc[2][3];
    #pragma unroll
    for (int i = 0; i < 2; ++i)
        #pragma unroll
        for (int j = 0; j < 3; ++j) acc[i][j] = (f32x4){0.f, 0.f, 0.f, 0.f};

    #pragma unroll
    for (int ib = 0; ib < 3; ++ib) {
        int row = w * 24 + ib * 8 + brl;
        int ch = bch ^ (row & 7);
        gl2lds16(Wbase + (size_t)row * 1024 + ch * 8, &su.s.b[0][(w * 3 + ib) * 512]);
    }
    {
        float4 f0 = *(const float4*)aSrc;
        float4 f1 = *(const float4*)(aSrc + 4);
        bf16x8 av;
        av[0] = (__bf16)f0.x; av[1] = (__bf16)f0.y; av[2] = (__bf16)f0.z; av[3] = (__bf16)f0.w;
        av[4] = (__bf16)f1.x; av[5] = (__bf16)f1.y; av[6] = (__bf16)f1.z; av[7] = (__bf16)f1.w;
        *(bf16x8*)&su.s.a[0][aDst] = av;
    }
    __syncthreads();

    for (int t = 0; t < 16; ++t) {
        int cur = t & 1;
        float4 g0, g1;
        if (t < 15) {
            int k0 = (t + 1) * 64;
            #pragma unroll
            for (int ib = 0; ib < 3; ++ib) {
                int row = w * 24 + ib * 8 + brl;
                int ch = bch ^ (row & 7);
                gl2lds16(Wbase + (size_t)row * 1024 + k0 + ch * 8,
                         &su.s.b[cur ^ 1][(w * 3 + ib) * 512]);
            }
            g0 = *(const float4*)(aSrc + k0);
            g1 = *(const float4*)(aSrc + k0 + 4);
        }
        #pragma unroll
        for (int kk = 0; kk < 2; ++kk) {
            bf16x8 a0 = *(const bf16x8*)&su.s.a[cur][(wm * 32 + c) * 64 + ((kk * 32 + hi * 8) ^ xorv)];
            bf16x8 a1 = *(const bf16x8*)&su.s.a[cur][(wm * 32 + 16 + c) * 64 + ((kk * 32 + hi * 8) ^ xorv)];
            #pragma unroll
            for (int fn = 0; fn < 3; ++fn) {
                bf16x8 bb = *(const bf16x8*)&su.s.b[cur][(wn * 48 + fn * 16 + c) * 64 + ((kk * 32 + hi * 8) ^ xorv)];
                acc[0][fn] = MFMA16(a0, bb, acc[0][fn], 0, 0, 0);
                acc[1][fn] = MFMA16(a1, bb, acc[1][fn], 0, 0, 0);
            }
        }
        if (t < 15) {
            bf16x8 av;
            av[0] = (__bf16)g0.x; av[1] = (__bf16)g0.y; av[2] = (__bf16)g0.z; av[3] = (__bf16)g0.w;
            av[4] = (__bf16)g1.x; av[5] = (__bf16)g1.y; av[6] = (__bf16)g1.z; av[7] = (__bf16)g1.w;
            *(bf16x8*)&su.s.a[cur ^ 1][aDst] = av;
        }
        __syncthreads();
    }

    #pragma unroll
    for (int mi = 0; mi < 2; ++mi) {
        int rowl = wm * 32 + mi * 16 + hi * 4;
        #pragma unroll
        for (int fn = 0; fn < 3; ++fn) {
            int nb = ny * 192 + wn * 48 + fn * 16;
            int mat = nb >> 7, colb = (nb & 127) + c;
            #pragma unroll
            for (int r = 0; r < 4; ++r) {
                __bf16 v = (__bf16)acc[mi][fn][r];
                if (mat == 0)      Qp[(size_t)(m0 + rowl + r) * H + colb] = v;
                else if (mat == 1) Kp[(size_t)(m0 + rowl + r) * H + colb] = v;
                else               su.vt_e[colb][rowl + r] = v;
            }
        }
    }
    __syncthreads();
    if (ny == 1) {
        int d = tid >> 2, tc = (tid & 3) * 16;
        int b = m0 >> 12, tl = m0 & (T - 1);
        __bf16* dst = VT + ((size_t)b * H + d) * T + tl + tc;
        const __bf16* s2 = &su.vt_e[d][tc];
        *(uint4*)dst = *(const uint4*)s2;
        *(uint4*)(dst + 8) = *(const uint4*)(s2 + 8);
    }
}

// -------- kernel 2: causal attention, 64 t-rows PER WAVE (fat waves) -------
// 256 blocks x 256 thr (4 waves = ws(2 s-halves) x sp(2 step parities)).
// Block = (b, part p, u); q-tile pair {u, 63-u} (65 steps -> balanced).
// Each wave owns ALL 64 t-rows (kb2[2][8], oc[2][4]) so each step's 16
// loads serve 2x the MFMA work -> per-CU load-instruction count halves
// (the r15/r18-diagnosed memory-pipe transaction ceiling). VGPR ~320,
// 1 wave/SIMD by design (launch_bounds(256,1): 512-reg budget, no spill).
// Swapped-QK, in-register P (pk2+shfl_xor(32)). Direct-L2 Q/V; XCD pin.
__global__ __launch_bounds__(256, 1) void k_attn(
    const __bf16* __restrict__ Ka, const __bf16* __restrict__ Qb,
    const __bf16* __restrict__ VT, float* __restrict__ Out,
    float* __restrict__ Po, float* __restrict__ Pl)
{
    __shared__ float oacc[64][132];
    __shared__ float sml[4][64];

    const int tid = threadIdx.x, lane = tid & 63, w = tid >> 6;  // w 0..3
    const int t31 = lane & 31, hi5 = lane >> 5;
    const int ws = w >> 1, sp = w & 1;

    const int bi = blockIdx.x;
    const int p = bi & 1, b = (bi >> 1) & 3, u = bi >> 3;   // u in 0..31

    const __bf16* Kb  = Ka + (size_t)b * T * H;
    const __bf16* Qbb = Qb + (size_t)b * T * H;
    const __bf16* Vb  = VT + (size_t)b * H * T;

    #pragma unroll 1
    for (int half = 0; half < 2; ++half) {
        const int j  = half ? (63 - u) : u;
        const int t0 = j * 64;
        const int nsteps = j + 1;           // 64-wide s-steps

        // K B-fragments: all 64 t-rows, full H (64 VGPRs)
        bf16x8 kb2[2][8];
        #pragma unroll
        for (int tt = 0; tt < 2; ++tt)
            #pragma unroll
            for (int kc = 0; kc < 8; ++kc)
                kb2[tt][kc] = *(const bf16x8*)(Kb + (size_t)(t0 + tt * 32 + t31) * H + kc * 16 + hi5 * 8);

        f32x16 oc[2][4];
        #pragma unroll
        for (int tt = 0; tt < 2; ++tt)
            #pragma unroll
            for (int dn = 0; dn < 4; ++dn)
                #pragma unroll
                for (int r = 0; r < 16; ++r) oc[tt][dn][r] = 0.f;
        float ol0 = 0.f, ol1 = 0.f;

        for (int i = p + 2 * sp; i < nsteps; i += 4) {
            const int sbase = i * 64 + ws * 32;
            // Q A-frags (32 s-rows) + V B-frags, direct from L2 (16 loads)
            bf16x8 qa[8];
            #pragma unroll
            for (int kc = 0; kc < 8; ++kc)
                qa[kc] = *(const bf16x8*)(Qbb + (size_t)(sbase + t31) * H + kc * 16 + hi5 * 8);
            bf16x8 vb[4][2];
            #pragma unroll
            for (int dn = 0; dn < 4; ++dn)
                #pragma unroll
                for (int ks = 0; ks < 2; ++ks)
                    vb[dn][ks] = *(const bf16x8*)(Vb + (size_t)(dn * 32 + t31) * T + sbase + ks * 16 + hi5 * 8);

            #pragma unroll
            for (int tt = 0; tt < 2; ++tt) {
                const int tg = t0 + tt * 32 + t31;
                // QK^T (swapped): C[s][t], two 4-deep chains
                f32x16 accA, accB;
                #pragma unroll
                for (int r = 0; r < 16; ++r) { accA[r] = 0.f; accB[r] = 0.f; }
                #pragma unroll
                for (int kc = 0; kc < 4; ++kc) accA = MFMA32(qa[kc], kb2[tt][kc], accA, 0, 0, 0);
                #pragma unroll
                for (int kc = 4; kc < 8; ++kc) accB = MFMA32(qa[kc], kb2[tt][kc], accB, 0, 0, 0);

                // exp2 + causal mask + in-lane row sums
                const bool dz = (sbase + 31 >= t0 + tt * 32);
                float pv[16];
                #pragma unroll
                for (int r = 0; r < 16; ++r) {
                    float e = __builtin_amdgcn_exp2f(accA[r] + accB[r]);
                    if (dz) {
                        int sg = sbase + (r & 3) + 8 * (r >> 2) + 4 * hi5;
                        if (sg > tg) e = 0.f;
                    }
                    pv[r] = e;
                }
                float rs = ((pv[0] + pv[1]) + (pv[2] + pv[3])) + ((pv[4] + pv[5]) + (pv[6] + pv[7]))
                         + ((pv[8] + pv[9]) + (pv[10] + pv[11])) + ((pv[12] + pv[13]) + (pv[14] + pv[15]));
                if (tt == 0) ol0 += rs; else ol1 += rs;

                // pack P -> bf16 A-frags via lane^32 exchange (no LDS)
                unsigned x1 = pk2(pv[0], pv[1]),  x2 = pk2(pv[2], pv[3]);
                unsigned y1 = pk2(pv[4], pv[5]),  y2 = pk2(pv[6], pv[7]);
                unsigned x3 = pk2(pv[8], pv[9]),  x4 = pk2(pv[10], pv[11]);
                unsigned y3 = pk2(pv[12], pv[13]), y4 = pk2(pv[14], pv[15]);
                unsigned sx1 = __shfl_xor((int)x1, 32), sx2 = __shfl_xor((int)x2, 32);
                unsigned sy1 = __shfl_xor((int)y1, 32), sy2 = __shfl_xor((int)y2, 32);
                unsigned sx3 = __shfl_xor((int)x3, 32), sx4 = __shfl_xor((int)x4, 32);
                unsigned sy3 = __shfl_xor((int)y3, 32), sy4 = __shfl_xor((int)y4, 32);
                u32x4 wA, wB;
                wA[0] = hi5 ? sy1 : x1;  wA[1] = hi5 ? sy2 : x2;
                wA[2] = hi5 ? y1 : sx1;  wA[3] = hi5 ? y2 : sx2;
                wB[0] = hi5 ? sy3 : x3;  wB[1] = hi5 ? sy4 : x4;
                wB[2] = hi5 ? y3 : sx3;  wB[3] = hi5 ? y4 : sx4;
                bf16x8 paA = __builtin_bit_cast(bf16x8, wA);
                bf16x8 paB = __builtin_bit_cast(bf16x8, wB);

                // PV: O[t][d] += P(32x32) @ V(32x128)
                #pragma unroll
                for (int dn = 0; dn < 4; ++dn) {
                    oc[tt][dn] = MFMA32(paA, vb[dn][0], oc[tt][dn], 0, 0, 0);
                    oc[tt][dn] = MFMA32(paB, vb[dn][1], oc[tt][dn], 0, 0, 0);
                }
            }
        }

        // ---- merge hi-halves' row sums; 4-stage oc merge across waves ----
        ol0 += __shfl_xor(ol0, 32);
        ol1 += __shfl_xor(ol1, 32);
        if (lane < 32) { sml[w][t31] = ol0; sml[w][32 + t31] = ol1; }

        for (int g = 0; g < 4; ++g) {
            __syncthreads();
            if (w == g) {
                #pragma unroll
                for (int tt = 0; tt < 2; ++tt)
                    #pragma unroll
                    for (int dn = 0; dn < 4; ++dn)
                        #pragma unroll
                        for (int r = 0; r < 16; ++r) {
                            int row = tt * 32 + (r & 3) + 8 * (r >> 2) + 4 * hi5;
                            int col = dn * 32 + t31;
                            if (g == 0) oacc[row][col]  = oc[tt][dn][r];
                            else        oacc[row][col] += oc[tt][dn][r];
                        }
            }
        }
        __syncthreads();
        {
            int row = tid >> 2, col0 = (tid & 3) * 32;   // 64 rows x 128 cols
            float L = sml[0][row] + sml[1][row] + sml[2][row] + sml[3][row];
            float* dst = (p == 0 ? Out : Po) + ((size_t)b * T + t0 + row) * H + col0;
            #pragma unroll
            for (int k = 0; k < 32; k += 4) {
                float4 v;
                v.x = oacc[row][col0 + k];
                v.y = oacc[row][col0 + k + 1];
                v.z = oacc[row][col0 + k + 2];
                v.w = oacc[row][col0 + k + 3];
                *(float4*)(dst + k) = v;
            }
            if ((tid & 3) == 0) Pl[(size_t)p * BT + b * T + t0 + row] = L;
        }
        __syncthreads();   // oacc/sml safe to reuse in next half
    }
}

// -------- kernel 3: merge parts + normalize --------------------------------
__global__ __launch_bounds__(256) void k_merge(
    float* __restrict__ Out, const float* __restrict__ Po,
    const float* __restrict__ Pl)
{
    size_t idx = ((size_t)blockIdx.x * 256 + threadIdx.x) * 8;
    size_t row = idx >> 7;
    float inv = 1.0f / (Pl[row] + Pl[BT + row]);
    float4 a0 = *(const float4*)(Out + idx);
    float4 a1 = *(const float4*)(Out + idx + 4);
    float4 p0 = *(const float4*)(Po + idx);
    float4 p1 = *(const float4*)(Po + idx + 4);
    float4 r0, r1;
    r0.x = (a0.x + p0.x) * inv; r0.y = (a0.y + p0.y) * inv;
    r0.z = (a0.z + p0.z) * inv; r0.w = (a0.w + p0.w) * inv;
    r1.x = (a1.x + p1.x) * inv; r1.y = (a1.y + p1.y) * inv;
    r1.z = (a1.z + p1.z) * inv; r1.w = (a1.w + p1.w) * inv;
    *(float4*)(Out + idx)     = r0;
    *(float4*)(Out + idx + 4) = r1;
}

extern "C" void kernel_launch(void* const* d_in, const int* in_sizes, int n_in,
                              void* d_out, int out_size, void* d_ws, size_t ws_size,
                              hipStream_t stream) {
    const float* ix = (const float*)d_in[0];
    const float* Wq = (const float*)d_in[1];
    const float* Wk = (const float*)d_in[2];
    const float* Wv = (const float*)d_in[3];
    float* out = (float*)d_out;

    __bf16* WTall = (__bf16*)d_ws;                    // 384*1024
    __bf16* Qp = WTall + 393216;                      // [BT][H]
    __bf16* Kp = Qp + (size_t)BT * H;
    __bf16* VT = Kp + (size_t)BT * H;                 // [B][H][T]
    float*  Po = (float*)(VT + (size_t)BT * H);       // [BT][H] fp32
    float*  Pl = Po + (size_t)BT * H;                 // [2][BT]
    // total ws ~21.9 MB (known-good layout)

    k_wprep<<<dim3(1536), 256, 0, stream>>>(Wq, Wk, Wv, WTall);
    k_proj<<<dim3(512), 512, 0, stream>>>(ix, WTall, Qp, Kp, VT);
    k_attn<<<dim3(256), 256, 0, stream>>>(Kp, Qp, VT, out, Po, Pl);
    k_merge<<<dim3(1024), 256, 0, stream>>>(out, Po, Pl);
}